// Round 1
// baseline (1573.239 us; speedup 1.0000x reference)
//
#include <hip/hip_runtime.h>
#include <hip/hip_cooperative_groups.h>

namespace cg = cooperative_groups;

#define B 64
#define SLEN 768
#define NHID 1024
#define K2 2048
#define NTOK 32000
#define PADTOK (NTOK-1)
#define MAXL 16
#define MAXN 256
#define NINT 256
#define NCONV 128                 // W-conversion blocks inside dispatch 1
#define LEAFROWS (B*SLEN)         // position-keyed leaf rows

typedef unsigned short u16;
typedef unsigned int u32;
typedef __attribute__((ext_vector_type(8))) short short8;
typedef __attribute__((ext_vector_type(4))) float f32x4;

__device__ __forceinline__ u16 f2b(float f) {
  union { float f; u32 i; } v; v.f = f;
  u32 x = v.i;
  return (u16)((x + 0x7FFFu + ((x >> 16) & 1u)) >> 16);
}
__device__ __forceinline__ float fast_tanh(float x) {
  float t = __expf(2.0f * x);
  return 1.0f - 2.0f / (t + 1.0f);
}
__device__ __forceinline__ void glds16(const void* g, void* l) {
  __builtin_amdgcn_global_load_lds(
      (const __attribute__((address_space(1))) void*)g,
      (__attribute__((address_space(3))) void*)l, 16, 0, 0);
}

// ---------------------------------------------------------------------------
// Dispatch 1 (fused): block 0 = structural parse (batch-invariant);
// blocks 1..NCONV = W fp32->bf16; blocks NCONV+1.. = POSITION-KEYED leaf
// gather (leaf-ness decided from the token value alone -> no parse dep,
// fully overlapped). Leaf refs now encode POSITION: 0x40000000 | t.
// ---------------------------------------------------------------------------
__launch_bounds__(768)
__global__ void parse_leaf_wconv(const int* __restrict__ tokens,
                                 const float* __restrict__ emb,
                                 const float* __restrict__ W,
                                 int* __restrict__ cnt,      // [MAXL]
                                 int* __restrict__ rootArr,  // [1]
                                 int4* __restrict__ nodes,   // [MAXL][MAXN]
                                 u16* __restrict__ Wbf,
                                 u16* __restrict__ LeafVals) { // [B][SLEN][NHID]
  if (blockIdx.x > NCONV) {
    // leaf gather: 3 (b,pos) rows per 768-thread block
    int r = (blockIdx.x - 1 - NCONV) * 3 + (threadIdx.x >> 8);
    if (r >= LEAFROWS) return;
    int b = r / SLEN, t = r - b * SLEN;
    int tok = tokens[t * B + b];
    if (tok < 2 || tok == PADTOK) return;   // not a leaf position
    const float* src = emb + (size_t)tok * NHID;
    u16* dst = LeafVals + (size_t)r * NHID;
    int i = (threadIdx.x & 255) * 4;
    float4 v = *reinterpret_cast<const float4*>(src + i);
    ushort4 o = {f2b(v.x), f2b(v.y), f2b(v.z), f2b(v.w)};
    *reinterpret_cast<ushort4*>(dst + i) = o;
    return;
  }
  if (blockIdx.x != 0) {
    // W conversion
    int id = (blockIdx.x - 1) * 768 + threadIdx.x;
    int stride = NCONV * 768;
    for (int i = id; i < (NHID * K2) / 4; i += stride) {
      float4 v = reinterpret_cast<const float4*>(W)[i];
      ushort4 o = {f2b(v.x), f2b(v.y), f2b(v.z), f2b(v.w)};
      reinterpret_cast<ushort4*>(Wbf)[i] = o;
    }
    return;
  }

  // ---- block 0: parallel structural parse (batch 0; structure invariant) ----
  __shared__ int tok[SLEN];
  __shared__ int SC[SLEN];        // packed scan: depth<<20 | leaf<<10 | close
  __shared__ short A[16 * SLEN];  // per-depth max-scan; later lvl overlay
  __shared__ int cntLoc[MAXL];

  int t = threadIdx.x;
  tok[t] = tokens[t * B + 0];
  if (t < MAXL) cntLoc[t] = 0;
  __syncthreads();

  int tk = tok[t];
  bool isO = (tk == 0), isC = (tk == 1);
  bool isL = !isO && !isC && (tk != PADTOK);
  int delta = isO ? 1 : (isC ? -1 : 0);
  SC[t] = (delta << 20) + ((isL ? 1 : 0) << 10) + (isC ? 1 : 0);
  __syncthreads();

  for (int off = 1; off < SLEN; off <<= 1) {   // packed inclusive scan
    int v = SC[t];
    int u = (t >= off) ? SC[t - off] : 0;
    __syncthreads();
    SC[t] = v + u;
    __syncthreads();
  }

  int S = SC[t];
  int depth = S >> 20; if (depth > 15) depth = 15;
  int clIdx = S & 1023;

  // per-depth max scans: A[d][t] = max{t' <= t : D[t'] == d}, else -1
#pragma unroll
  for (int d = 0; d < 16; ++d) A[d * SLEN + t] = (depth == d) ? (short)t : (short)-1;
  __syncthreads();
  for (int off = 1; off < SLEN; off <<= 1) {
    short vv[16];
#pragma unroll
    for (int d = 0; d < 16; ++d) {
      short a = A[d * SLEN + t];
      if (t >= off) { short b2 = A[d * SLEN + t - off]; a = (a > b2) ? a : b2; }
      vv[d] = a;
    }
    __syncthreads();
#pragma unroll
    for (int d = 0; d < 16; ++d) A[d * SLEN + t] = vv[d];
    __syncthreads();
  }

  // per-CLOSE child refs (leaf children -> POSITION encoding)
  int myid = -1, lref = 0, rref = 0, lce = -1;
  bool rIsLeaf = false, lIsLeaf = false;
  if (isC && t >= 3) {
    myid = clIdx - 1;
    int tm1 = tok[t - 1];
    rIsLeaf = (tm1 != 1);
    rref = rIsLeaf ? (0x40000000 | (t - 1)) : ((SC[t - 1] & 1023) - 1);
    int dd = depth + 1; if (dd > 15) dd = 15;
    lce = rIsLeaf ? (t - 2) : (int)A[dd * SLEN + (t - 2)];
    if (lce >= 0) {
      lIsLeaf = (tok[lce] != 1);
      lref = lIsLeaf ? (0x40000000 | lce) : ((SC[lce] & 1023) - 1);
    }
  }
  __syncthreads();

  // level sweeps (lvl overlays A row 0)
  short* lvl = A;
  lvl[t] = isC ? (short)1 : (short)0;
  __syncthreads();
  int lv = 1;
  for (int it = 0; it < 15; ++it) {
    if (myid >= 0) {
      int ll = lIsLeaf ? 0 : (int)lvl[lce];
      int rr = rIsLeaf ? 0 : (int)lvl[t - 1];
      lv = (ll > rr ? ll : rr) + 1;
    }
    __syncthreads();
    if (myid >= 0) lvl[t] = (short)lv;
    __syncthreads();
  }
  if (lv > 15) lv = 15;

  if (myid >= 0 && myid < NINT) {
    int slot = atomicAdd(&cntLoc[lv], 1);
    if (slot < MAXN)
      nodes[lv * MAXN + slot] = make_int4(lref, rref, myid, 0);
  }
  __syncthreads();

  if (t == 0) {
    int ncount = SC[SLEN - 1] & 1023;
    rootArr[0] = (ncount > 0) ? (ncount - 1 < NINT ? ncount - 1 : NINT - 1)
                              : 0x40000000;  // degenerate: root = leaf at pos 0
  }
  if (t >= 1 && t < MAXL) cnt[t] = (cntLoc[t] < MAXN) ? cntLoc[t] : MAXN;
}

// ---------------------------------------------------------------------------
// Shared tile body: 128x128 output tile, BK=64 as two 32-k panels, 4 waves,
// bf16 MFMA fp32 acc, tanh epilogue. Identical math to the previous kernel.
// ---------------------------------------------------------------------------
__device__ __forceinline__ void do_tile(int tile, int level, int cnt0, int rowsTotal,
                                        const u16* __restrict__ Wbf,
                                        const float* __restrict__ bias,
                                        const int4* __restrict__ nodes, int rootId,
                                        const u16* __restrict__ LeafVals,
                                        u16* __restrict__ Vals,
                                        float* __restrict__ out,
                                        short* As, short* Bs,
                                        const u16** sL, const u16** sR,
                                        int* sOut, int* sRoot) {
  int tid = threadIdx.x;
  int lane = tid & 63, wave = tid >> 6;
  int wm = wave & 1, wn = wave >> 1;
  int mt = tile >> 3, nt = tile & 7;
  int m0 = mt << 7, n0 = nt << 7;
  __syncthreads();  // protect sL/sR/sOut vs previous tile's readers
  if (tid < 128) {
    int r = m0 + tid;
    const u16* lp = Wbf; const u16* rp = Wbf; int ov = -1, rf = -1;
    if (r < rowsTotal) {
      int bb = r / cnt0, j = r - bb * cnt0;
      int4 rec = nodes[level * MAXN + j];
      int lr = rec.x, rr = rec.y;
      lp = (lr & 0x40000000) ? LeafVals + (size_t)(bb * SLEN + (lr & 0xFFFF)) * NHID
                             : Vals + ((size_t)bb * NINT + lr) * NHID;
      rp = (rr & 0x40000000) ? LeafVals + (size_t)(bb * SLEN + (rr & 0xFFFF)) * NHID
                             : Vals + ((size_t)bb * NINT + rr) * NHID;
      ov = bb * NINT + rec.z;
      if (rec.z == rootId) rf = bb * NHID;
    }
    sL[tid] = lp; sR[tid] = rp; sOut[tid] = ov; sRoot[tid] = rf;
  }
  __syncthreads();

  int kq = (tid & 3) * 8;
  const u16* a0L = sL[tid >> 2] + kq;        const u16* a0R = sR[tid >> 2] + kq;
  const u16* a1L = sL[64 + (tid >> 2)] + kq; const u16* a1R = sR[64 + (tid >> 2)] + kq;
  const u16* b0 = Wbf + (size_t)(n0 + (tid >> 2)) * K2 + kq;
  const u16* b1 = Wbf + (size_t)(n0 + 64 + (tid >> 2)) * K2 + kq;
  short* AsW = As + wave * 512;  // wave-uniform LDS dest
  short* BsW = Bs + wave * 512;

  f32x4 acc[4][4];
#pragma unroll
  for (int i = 0; i < 4; ++i)
#pragma unroll
    for (int j = 0; j < 4; ++j) acc[i][j] = {0.f, 0.f, 0.f, 0.f};

  int aBase = (wm * 64 + (lane & 15)) * 32 + (lane >> 4) * 8;
  int bBase = (wn * 64 + (lane & 15)) * 32 + (lane >> 4) * 8;

  for (int k0 = 0; k0 < K2; k0 += 64) {
#pragma unroll
    for (int p = 0; p < 2; ++p) {
      int k = k0 + p * 32;  // NHID%64==0 -> panel fully on one side
      const u16* sa0 = (k < NHID) ? (a0L + k) : (a0R + (k - NHID));
      const u16* sa1 = (k < NHID) ? (a1L + k) : (a1R + (k - NHID));
      glds16(sa0, AsW + p * 4096);
      glds16(sa1, AsW + p * 4096 + 2048);
      glds16(b0 + k, BsW + p * 4096);
      glds16(b1 + k, BsW + p * 4096 + 2048);
    }
    __syncthreads();
#pragma unroll
    for (int p = 0; p < 2; ++p) {
      short8 af[4], bw[4];
#pragma unroll
      for (int mi = 0; mi < 4; ++mi)
        af[mi] = *reinterpret_cast<const short8*>(As + p * 4096 + aBase + mi * 512);
#pragma unroll
      for (int ni = 0; ni < 4; ++ni)
        bw[ni] = *reinterpret_cast<const short8*>(Bs + p * 4096 + bBase + ni * 512);
#pragma unroll
      for (int mi = 0; mi < 4; ++mi)
#pragma unroll
        for (int ni = 0; ni < 4; ++ni)
          acc[mi][ni] = __builtin_amdgcn_mfma_f32_16x16x32_bf16(
              af[mi], bw[ni], acc[mi][ni], 0, 0, 0);
    }
    __syncthreads();
  }

  // epilogue: C/D layout col=lane&15 (n), row=(lane>>4)*4+reg (m)
#pragma unroll
  for (int ni = 0; ni < 4; ++ni) {
    int n = n0 + wn * 64 + ni * 16 + (lane & 15);
    float bv = bias[n];
#pragma unroll
    for (int mi = 0; mi < 4; ++mi) {
#pragma unroll
      for (int reg = 0; reg < 4; ++reg) {
        int mloc = wm * 64 + mi * 16 + (lane >> 4) * 4 + reg;
        int ov = sOut[mloc];
        if (ov >= 0) {
          float v = fast_tanh(acc[mi][ni][reg] + bv);
          Vals[(size_t)ov * NHID + n] = f2b(v);
          int rf = sRoot[mloc];
          if (rf >= 0) out[rf + n] = v;  // root row -> final output (fp32)
        }
      }
    }
  }
}

// ---------------------------------------------------------------------------
// Dispatch 2: ALL levels in one cooperative kernel; grid.sync between levels.
// 512 blocks (==L1 tile count), 2 blocks/CU co-resident by construction:
// LDS 35.8 KB x2 <= 160 KB, __launch_bounds__(256,2) caps VGPR at 256.
// ---------------------------------------------------------------------------
__launch_bounds__(256, 2)
__global__ void combine_all(const u16* __restrict__ Wbf,
                            const float* __restrict__ bias,
                            const int* __restrict__ cnt,
                            const int4* __restrict__ nodes,
                            const int* __restrict__ rootArr,
                            const u16* __restrict__ LeafVals,
                            u16* __restrict__ Vals,
                            float* __restrict__ out,
                            const int* __restrict__ tokens,
                            const float* __restrict__ emb) {
  cg::grid_group grid = cg::this_grid();
  __shared__ short As[8192];
  __shared__ short Bs[8192];
  __shared__ const u16* sL[128];
  __shared__ const u16* sR[128];
  __shared__ int sOut[128];
  __shared__ int sRoot[128];

  int rootId = rootArr[0];
  if (rootId & 0x40000000) {   // degenerate single-leaf tree: copy emb row fp32
    int pos = rootId & 0xFFFF;
    for (int b = blockIdx.x; b < B; b += gridDim.x) {
      int tokv = tokens[pos * B + b];
      for (int i = threadIdx.x; i < NHID; i += 256)
        out[(size_t)b * NHID + i] = emb[(size_t)tokv * NHID + i];
    }
    return;  // cnt[1..] == 0 grid-wide -> no syncs executed by anyone
  }

  for (int level = 1; level < MAXL; ++level) {
    int cnt0 = cnt[level];          // uniform across grid
    if (cnt0 <= 0) break;
    int rowsTotal = B * cnt0;
    int mTiles = (rowsTotal + 127) >> 7;
    int totalTiles = mTiles * 8;
    for (int tile = blockIdx.x; tile < totalTiles; tile += gridDim.x)
      do_tile(tile, level, cnt0, rowsTotal, Wbf, bias, nodes, rootId,
              LeafVals, Vals, out, As, Bs, sL, sR, sOut, sRoot);
    __threadfence();   // release Vals writes device-wide (cross-XCD L2)
    grid.sync();
    __threadfence();   // acquire before reading previous level's Vals
  }
}

// Fallback (non-cooperative, one dispatch per level) — used only if the
// cooperative launch is rejected at enqueue time.
__launch_bounds__(256, 3)
__global__ void combine_level(const u16* __restrict__ Wbf,
                              const float* __restrict__ bias,
                              const int* __restrict__ cnt,
                              const int4* __restrict__ nodes,
                              const int* __restrict__ rootArr,
                              const u16* __restrict__ LeafVals,
                              u16* __restrict__ Vals,
                              float* __restrict__ out,
                              int level) {
  __shared__ short As[8192];
  __shared__ short Bs[8192];
  __shared__ const u16* sL[128];
  __shared__ const u16* sR[128];
  __shared__ int sOut[128];
  __shared__ int sRoot[128];
  int cnt0 = cnt[level];
  if (cnt0 <= 0) return;
  int rowsTotal = B * cnt0;
  int mTiles = (rowsTotal + 127) >> 7;
  int totalTiles = mTiles * 8;
  int rootId = rootArr[0];
  for (int tile = blockIdx.x; tile < totalTiles; tile += gridDim.x)
    do_tile(tile, level, cnt0, rowsTotal, Wbf, bias, nodes, rootId,
            LeafVals, Vals, out, As, Bs, sL, sR, sOut, sRoot);
}

extern "C" void kernel_launch(void* const* d_in, const int* in_sizes, int n_in,
                              void* d_out, int out_size, void* d_ws, size_t ws_size,
                              hipStream_t stream) {
  const int* tokens = (const int*)d_in[0];
  const float* emb  = (const float*)d_in[1];
  const float* W    = (const float*)d_in[2];
  const float* bias = (const float*)d_in[3];
  float* out = (float*)d_out;

  char* ws = (char*)d_ws;
  // ws layout (bytes):
  //   cnt      @ 0           64 B
  //   rootArr  @ 4096        4 B
  //   nodes    @ 12288       64 KB  ([MAXL][MAXN] int4, batch-invariant)
  //   Wbf      @ 131072      4 MB
  //   LeafVals @ 4325376     96 MB  (position-keyed: [B][SLEN][NHID] bf16)
  //   Vals     @ +96MB       32 MB  -> total ~138.5 MB
  int* cnt      = (int*)ws;
  int* rootArr  = (int*)(ws + 4096);
  int4* nodes   = (int4*)(ws + 12288);
  u16* Wbf      = (u16*)(ws + 131072);
  u16* LeafVals = (u16*)(ws + 4325376);
  u16* Vals     = (u16*)(ws + 4325376 + (size_t)B * SLEN * NHID * 2);

  // Dispatch 1: parse (block 0) + W conversion (blocks 1..128) + leaf gather
  // (blocks 129..) all overlapped — leaf-ness needs only the token value.
  int leafBlocks = (LEAFROWS + 2) / 3;        // 16384
  parse_leaf_wconv<<<1 + NCONV + leafBlocks, 768, 0, stream>>>(
      tokens, emb, W, cnt, rootArr, nodes, Wbf, LeafVals);

  // Dispatch 2: all combine levels in one cooperative kernel.
  void* args[10];
  args[0] = (void*)&Wbf;      args[1] = (void*)&bias;
  args[2] = (void*)&cnt;      args[3] = (void*)&nodes;
  args[4] = (void*)&rootArr;  args[5] = (void*)&LeafVals;
  args[6] = (void*)&Vals;     args[7] = (void*)&out;
  args[8] = (void*)&tokens;   args[9] = (void*)&emb;
  hipError_t e = hipLaunchCooperativeKernel((const void*)combine_all,
                                            dim3(512), dim3(256), args, 0, stream);
  if (e != hipSuccess) {
    // Fallback: per-level dispatches (previous proven structure)
    for (int L = 1; L <= 9; ++L) {
      int expRows = B * (L <= 8 ? (256 >> L) : 1);
      int mT = (expRows + 127) / 128;
      combine_level<<<mT * 8, 256, 0, stream>>>(Wbf, bias, cnt, nodes, rootArr,
                                                LeafVals, Vals, out, L);
    }
  }
}

// Round 2
// 621.207 us; speedup vs baseline: 2.5326x; 2.5326x over previous
//
#include <hip/hip_runtime.h>

#define B 64
#define SLEN 768
#define NHID 1024
#define K2 2048
#define NTOK 32000
#define PADTOK (NTOK-1)
#define MAXL 16
#define MAXN 256
#define NINT 256
#define NCONV 128                 // W-conversion blocks inside dispatch 1
#define LEAFB 2048                // leaf-gather blocks (grid-strided)
#define LEAFROWS (B*SLEN)         // position-keyed leaf rows

typedef unsigned short u16;
typedef unsigned int u32;
typedef __attribute__((ext_vector_type(8))) short short8;
typedef __attribute__((ext_vector_type(4))) float f32x4;

__device__ __forceinline__ u16 f2b(float f) {
  union { float f; u32 i; } v; v.f = f;
  u32 x = v.i;
  return (u16)((x + 0x7FFFu + ((x >> 16) & 1u)) >> 16);
}
__device__ __forceinline__ float fast_tanh(float x) {
  float t = __expf(2.0f * x);
  return 1.0f - 2.0f / (t + 1.0f);
}
__device__ __forceinline__ void glds16(const void* g, void* l) {
  __builtin_amdgcn_global_load_lds(
      (const __attribute__((address_space(1))) void*)g,
      (__attribute__((address_space(3))) void*)l, 16, 0, 0);
}

// ---------------------------------------------------------------------------
// Dispatch 1 (fused): block 0 = structural parse (batch-invariant);
// blocks 1..NCONV = W fp32->bf16; blocks NCONV+1..NCONV+LEAFB = position-keyed
// leaf gather (leaf-ness from token value alone -> no parse dependency, fully
// overlapped). Leaf refs encode POSITION: 0x40000000 | t.
// ---------------------------------------------------------------------------
__launch_bounds__(768)
__global__ void parse_leaf_wconv(const int* __restrict__ tokens,
                                 const float* __restrict__ emb,
                                 const float* __restrict__ W,
                                 int* __restrict__ cnt,      // [MAXL]
                                 int* __restrict__ rootArr,  // [1]
                                 int4* __restrict__ nodes,   // [MAXL][MAXN]
                                 u16* __restrict__ Wbf,
                                 u16* __restrict__ LeafVals) { // [B][SLEN][NHID]
  if (blockIdx.x > NCONV) {
    // leaf gather: 3 rows per block-iteration (256 threads per row), strided
    int base = (blockIdx.x - 1 - NCONV) * 3 + (threadIdx.x >> 8);
    int i = (threadIdx.x & 255) * 4;
    for (int r = base; r < LEAFROWS; r += LEAFB * 3) {
      int b = r / SLEN, t = r - b * SLEN;
      int tok = tokens[t * B + b];
      if (tok < 2 || tok == PADTOK) continue;   // not a leaf position
      const float* src = emb + (size_t)tok * NHID;
      u16* dst = LeafVals + (size_t)r * NHID;
      float4 v = *reinterpret_cast<const float4*>(src + i);
      ushort4 o = {f2b(v.x), f2b(v.y), f2b(v.z), f2b(v.w)};
      *reinterpret_cast<ushort4*>(dst + i) = o;
    }
    return;
  }
  if (blockIdx.x != 0) {
    // W conversion
    int id = (blockIdx.x - 1) * 768 + threadIdx.x;
    int stride = NCONV * 768;
    for (int i = id; i < (NHID * K2) / 4; i += stride) {
      float4 v = reinterpret_cast<const float4*>(W)[i];
      ushort4 o = {f2b(v.x), f2b(v.y), f2b(v.z), f2b(v.w)};
      reinterpret_cast<ushort4*>(Wbf)[i] = o;
    }
    return;
  }

  // ---- block 0: parallel structural parse (batch 0; structure invariant) ----
  __shared__ int tok[SLEN];
  __shared__ int SC[SLEN];        // packed scan: depth<<20 | leaf<<10 | close
  __shared__ short A[16 * SLEN];  // per-depth max-scan; later lvl overlay
  __shared__ int cntLoc[MAXL];

  int t = threadIdx.x;
  tok[t] = tokens[t * B + 0];
  if (t < MAXL) cntLoc[t] = 0;
  __syncthreads();

  int tk = tok[t];
  bool isO = (tk == 0), isC = (tk == 1);
  bool isL = !isO && !isC && (tk != PADTOK);
  int delta = isO ? 1 : (isC ? -1 : 0);
  SC[t] = (delta << 20) + ((isL ? 1 : 0) << 10) + (isC ? 1 : 0);
  __syncthreads();

  for (int off = 1; off < SLEN; off <<= 1) {   // packed inclusive scan
    int v = SC[t];
    int u = (t >= off) ? SC[t - off] : 0;
    __syncthreads();
    SC[t] = v + u;
    __syncthreads();
  }

  int S = SC[t];
  int depth = S >> 20; if (depth > 15) depth = 15;
  int clIdx = S & 1023;

  // per-depth max scans: A[d][t] = max{t' <= t : D[t'] == d}, else -1
#pragma unroll
  for (int d = 0; d < 16; ++d) A[d * SLEN + t] = (depth == d) ? (short)t : (short)-1;
  __syncthreads();
  for (int off = 1; off < SLEN; off <<= 1) {
    short vv[16];
#pragma unroll
    for (int d = 0; d < 16; ++d) {
      short a = A[d * SLEN + t];
      if (t >= off) { short b2 = A[d * SLEN + t - off]; a = (a > b2) ? a : b2; }
      vv[d] = a;
    }
    __syncthreads();
#pragma unroll
    for (int d = 0; d < 16; ++d) A[d * SLEN + t] = vv[d];
    __syncthreads();
  }

  // per-CLOSE child refs (leaf children -> POSITION encoding)
  int myid = -1, lref = 0, rref = 0, lce = -1;
  bool rIsLeaf = false, lIsLeaf = false;
  if (isC && t >= 3) {
    myid = clIdx - 1;
    int tm1 = tok[t - 1];
    rIsLeaf = (tm1 != 1);
    rref = rIsLeaf ? (0x40000000 | (t - 1)) : ((SC[t - 1] & 1023) - 1);
    int dd = depth + 1; if (dd > 15) dd = 15;
    lce = rIsLeaf ? (t - 2) : (int)A[dd * SLEN + (t - 2)];
    if (lce >= 0) {
      lIsLeaf = (tok[lce] != 1);
      lref = lIsLeaf ? (0x40000000 | lce) : ((SC[lce] & 1023) - 1);
    }
  }
  __syncthreads();

  // level sweeps (lvl overlays A row 0)
  short* lvl = A;
  lvl[t] = isC ? (short)1 : (short)0;
  __syncthreads();
  int lv = 1;
  for (int it = 0; it < 15; ++it) {
    if (myid >= 0) {
      int ll = lIsLeaf ? 0 : (int)lvl[lce];
      int rr = rIsLeaf ? 0 : (int)lvl[t - 1];
      lv = (ll > rr ? ll : rr) + 1;
    }
    __syncthreads();
    if (myid >= 0) lvl[t] = (short)lv;
    __syncthreads();
  }
  if (lv > 15) lv = 15;

  if (myid >= 0 && myid < NINT) {
    int slot = atomicAdd(&cntLoc[lv], 1);
    if (slot < MAXN)
      nodes[lv * MAXN + slot] = make_int4(lref, rref, myid, 0);
  }
  __syncthreads();

  if (t == 0) {
    int ncount = SC[SLEN - 1] & 1023;
    rootArr[0] = (ncount > 0) ? (ncount - 1 < NINT ? ncount - 1 : NINT - 1)
                              : 0x40000000;  // degenerate: root = leaf at pos 0
  }
  if (t >= 1 && t < MAXL) cnt[t] = (cntLoc[t] < MAXN) ? cntLoc[t] : MAXN;
}

// ---------------------------------------------------------------------------
// Per-level combine: out = tanh(concat(valL,valR) @ W^T + b), bf16 MFMA.
// 128x128 tile, BK=64, 4 waves. NEW: double-buffered LDS (2-phase pipeline,
// §5.5 T3 minimum recipe): stage k-step t+1 BEFORE computing step t, then one
// vmcnt(0)+raw-barrier per step — load latency hides under 32 MFMAs.
// nt = tile&7 with grid%8==0 keeps each XCD on one 512 KB W-stripe (L2-hot).
// ---------------------------------------------------------------------------
__launch_bounds__(256, 2)
__global__ void combine_level(const u16* __restrict__ Wbf,
                              const float* __restrict__ bias,
                              const int* __restrict__ cnt,
                              const int4* __restrict__ nodes,
                              const int* __restrict__ rootArr,
                              const u16* __restrict__ LeafVals,
                              u16* __restrict__ Vals,     // [B][NINT][NHID] bf16
                              float* __restrict__ out,    // [B][NHID] fp32
                              const int* __restrict__ tokens,
                              const float* __restrict__ emb,
                              int level) {
  __shared__ short As[2][8192];   // 2 stages x (2 panels x 128 rows x 32 k)
  __shared__ short Bs[2][8192];
  __shared__ const u16* sL[128];
  __shared__ const u16* sR[128];
  __shared__ int sOut[128];
  __shared__ int sRoot[128];

  int rootId = rootArr[0];
  if (rootId & 0x40000000) {       // degenerate single-leaf tree
    if (level != 1) return;
    int pos = rootId & 0xFFFF;
    for (int b = blockIdx.x; b < B; b += gridDim.x) {
      int tokv = tokens[pos * B + b];
      for (int i = threadIdx.x; i < NHID; i += 256)
        out[(size_t)b * NHID + i] = emb[(size_t)tokv * NHID + i];
    }
    return;
  }

  int cnt0 = cnt[level];
  if (cnt0 <= 0) return;
  int rowsTotal = B * cnt0;
  int mTiles = (rowsTotal + 127) >> 7;
  int totalTiles = mTiles * 8;
  int tid = threadIdx.x;
  int lane = tid & 63, wave = tid >> 6;
  int wm = wave & 1, wn = wave >> 1;

  for (int tile = blockIdx.x; tile < totalTiles; tile += gridDim.x) {
    int mt = tile >> 3, nt = tile & 7;
    int m0 = mt << 7, n0 = nt << 7;
    __syncthreads();  // protect sL/sR/sOut vs previous tile's readers
    if (tid < 128) {
      int r = m0 + tid;
      const u16* lp = Wbf; const u16* rp = Wbf; int ov = -1, rf = -1;
      if (r < rowsTotal) {
        int bb = r / cnt0, j = r - bb * cnt0;
        int4 rec = nodes[level * MAXN + j];
        int lr = rec.x, rr = rec.y;
        lp = (lr & 0x40000000) ? LeafVals + (size_t)(bb * SLEN + (lr & 0xFFFF)) * NHID
                               : Vals + ((size_t)bb * NINT + lr) * NHID;
        rp = (rr & 0x40000000) ? LeafVals + (size_t)(bb * SLEN + (rr & 0xFFFF)) * NHID
                               : Vals + ((size_t)bb * NINT + rr) * NHID;
        ov = bb * NINT + rec.z;
        if (rec.z == rootId) rf = bb * NHID;
      }
      sL[tid] = lp; sR[tid] = rp; sOut[tid] = ov; sRoot[tid] = rf;
    }
    __syncthreads();

    int kq = (tid & 3) * 8;
    const u16* a0L = sL[tid >> 2] + kq;        const u16* a0R = sR[tid >> 2] + kq;
    const u16* a1L = sL[64 + (tid >> 2)] + kq; const u16* a1R = sR[64 + (tid >> 2)] + kq;
    const u16* b0 = Wbf + (size_t)(n0 + (tid >> 2)) * K2 + kq;
    const u16* b1 = Wbf + (size_t)(n0 + 64 + (tid >> 2)) * K2 + kq;

    f32x4 acc[4][4];
#pragma unroll
    for (int i = 0; i < 4; ++i)
#pragma unroll
      for (int j = 0; j < 4; ++j) acc[i][j] = {0.f, 0.f, 0.f, 0.f};

    int aBase = (wm * 64 + (lane & 15)) * 32 + (lane >> 4) * 8;
    int bBase = (wn * 64 + (lane & 15)) * 32 + (lane >> 4) * 8;

    auto STAGE = [&](int buf, int k0) {
#pragma unroll
      for (int p = 0; p < 2; ++p) {
        int k = k0 + p * 32;  // NHID%64==0 -> panel fully on one side
        const u16* sa0 = (k < NHID) ? (a0L + k) : (a0R + (k - NHID));
        const u16* sa1 = (k < NHID) ? (a1L + k) : (a1R + (k - NHID));
        short* Ad = &As[buf][0] + p * 4096 + wave * 512;  // wave-uniform dest
        short* Bd = &Bs[buf][0] + p * 4096 + wave * 512;
        glds16(sa0, Ad);
        glds16(sa1, Ad + 2048);
        glds16(b0 + k, Bd);
        glds16(b1 + k, Bd + 2048);
      }
    };
    auto COMPUTE = [&](int buf) {
#pragma unroll
      for (int p = 0; p < 2; ++p) {
        short8 af[4], bw[4];
#pragma unroll
        for (int mi = 0; mi < 4; ++mi)
          af[mi] = *reinterpret_cast<const short8*>(&As[buf][0] + p * 4096 + aBase + mi * 512);
#pragma unroll
        for (int ni = 0; ni < 4; ++ni)
          bw[ni] = *reinterpret_cast<const short8*>(&Bs[buf][0] + p * 4096 + bBase + ni * 512);
#pragma unroll
        for (int mi = 0; mi < 4; ++mi)
#pragma unroll
          for (int ni = 0; ni < 4; ++ni)
            acc[mi][ni] = __builtin_amdgcn_mfma_f32_16x16x32_bf16(
                af[mi], bw[ni], acc[mi][ni], 0, 0, 0);
      }
    };

    // 2-stage pipeline over 32 K-steps of 64
    STAGE(0, 0);
    asm volatile("s_waitcnt vmcnt(0)" ::: "memory");
    __builtin_amdgcn_s_barrier();
    int cur = 0;
    for (int it = 0; it < 31; ++it) {
      STAGE(cur ^ 1, (it + 1) * 64);   // issue next stage first (hidden)
      COMPUTE(cur);                    // 16 ds_read_b128 + 32 MFMA
      asm volatile("s_waitcnt vmcnt(0)" ::: "memory");
      __builtin_amdgcn_s_barrier();
      cur ^= 1;
    }
    COMPUTE(cur);

    // epilogue: C/D layout col=lane&15 (n), row=(lane>>4)*4+reg (m)
#pragma unroll
    for (int ni = 0; ni < 4; ++ni) {
      int n = n0 + wn * 64 + ni * 16 + (lane & 15);
      float bv = bias[n];
#pragma unroll
      for (int mi = 0; mi < 4; ++mi) {
#pragma unroll
        for (int reg = 0; reg < 4; ++reg) {
          int mloc = wm * 64 + mi * 16 + (lane >> 4) * 4 + reg;
          int ov = sOut[mloc];
          if (ov >= 0) {
            float v = fast_tanh(acc[mi][ni][reg] + bv);
            Vals[(size_t)ov * NHID + n] = f2b(v);
            int rf = sRoot[mloc];
            if (rf >= 0) out[rf + n] = v;  // root row -> final output (fp32)
          }
        }
      }
    }
  }
}

extern "C" void kernel_launch(void* const* d_in, const int* in_sizes, int n_in,
                              void* d_out, int out_size, void* d_ws, size_t ws_size,
                              hipStream_t stream) {
  const int* tokens = (const int*)d_in[0];
  const float* emb  = (const float*)d_in[1];
  const float* W    = (const float*)d_in[2];
  const float* bias = (const float*)d_in[3];
  float* out = (float*)d_out;

  char* ws = (char*)d_ws;
  // ws layout (bytes):
  //   cnt      @ 0           64 B
  //   rootArr  @ 4096        4 B
  //   nodes    @ 12288       64 KB  ([MAXL][MAXN] int4, batch-invariant)
  //   Wbf      @ 131072      4 MB
  //   LeafVals @ 4325376     96 MB  (position-keyed: [B][SLEN][NHID] bf16)
  //   Vals     @ +96MB       32 MB  -> total ~138.5 MB
  int* cnt      = (int*)ws;
  int* rootArr  = (int*)(ws + 4096);
  int4* nodes   = (int4*)(ws + 12288);
  u16* Wbf      = (u16*)(ws + 131072);
  u16* LeafVals = (u16*)(ws + 4325376);
  u16* Vals     = (u16*)(ws + 4325376 + (size_t)B * SLEN * NHID * 2);

  // Dispatch 1: parse (block 0) + W conversion (blocks 1..128) + leaf gather
  // (2048 grid-strided blocks) all overlapped.
  parse_leaf_wconv<<<1 + NCONV + LEAFB, 768, 0, stream>>>(
      tokens, emb, W, cnt, rootArr, nodes, Wbf, LeafVals);

  // Dispatches 2..10: one per level (stream-ordered dependencies).
  for (int L = 1; L <= 9; ++L) {  // balanced 256-leaf tree: levels 1..8; 9 = guard
    int expRows = B * (L <= 8 ? (256 >> L) : 1);
    int mT = (expRows + 127) / 128;
    combine_level<<<mT * 8, 256, 0, stream>>>(Wbf, bias, cnt, nodes, rootArr,
                                              LeafVals, Vals, out, tokens, emb, L);
  }
}

// Round 3
// 600.528 us; speedup vs baseline: 2.6198x; 1.0344x over previous
//
#include <hip/hip_runtime.h>

#define B 64
#define SLEN 768
#define NHID 1024
#define K2 2048
#define NTOK 32000
#define PADTOK (NTOK-1)
#define MAXL 16
#define MAXN 256
#define NINT 256
#define NCONV 128                 // W-conversion blocks inside dispatch 1
#define LEAFB 2048                // leaf-gather blocks (grid-strided)
#define LEAFROWS (B*SLEN)         // position-keyed leaf rows

typedef unsigned short u16;
typedef unsigned int u32;
typedef __attribute__((ext_vector_type(8))) short short8;
typedef __attribute__((ext_vector_type(4))) float f32x4;

__device__ __forceinline__ u16 f2b(float f) {
  union { float f; u32 i; } v; v.f = f;
  u32 x = v.i;
  return (u16)((x + 0x7FFFu + ((x >> 16) & 1u)) >> 16);
}
__device__ __forceinline__ float fast_tanh(float x) {
  float t = __expf(2.0f * x);
  return 1.0f - 2.0f / (t + 1.0f);
}
__device__ __forceinline__ void glds16(const void* g, void* l) {
  __builtin_amdgcn_global_load_lds(
      (const __attribute__((address_space(1))) void*)g,
      (__attribute__((address_space(3))) void*)l, 16, 0, 0);
}

// ---------------------------------------------------------------------------
// Dispatch 1 (fused): block 0 = structural parse (batch-invariant);
// blocks 1..NCONV = W fp32->bf16; blocks NCONV+1..NCONV+LEAFB = position-keyed
// leaf gather (leaf-ness from token value alone -> no parse dependency, fully
// overlapped). Leaf refs encode POSITION: 0x40000000 | t.
// ---------------------------------------------------------------------------
__launch_bounds__(768)
__global__ void parse_leaf_wconv(const int* __restrict__ tokens,
                                 const float* __restrict__ emb,
                                 const float* __restrict__ W,
                                 int* __restrict__ cnt,      // [MAXL]
                                 int* __restrict__ rootArr,  // [1]
                                 int4* __restrict__ nodes,   // [MAXL][MAXN]
                                 u16* __restrict__ Wbf,
                                 u16* __restrict__ LeafVals) { // [B][SLEN][NHID]
  if (blockIdx.x > NCONV) {
    // leaf gather: 3 rows per block-iteration (256 threads per row), strided
    int base = (blockIdx.x - 1 - NCONV) * 3 + (threadIdx.x >> 8);
    int i = (threadIdx.x & 255) * 4;
    for (int r = base; r < LEAFROWS; r += LEAFB * 3) {
      int b = r / SLEN, t = r - b * SLEN;
      int tok = tokens[t * B + b];
      if (tok < 2 || tok == PADTOK) continue;   // not a leaf position
      const float* src = emb + (size_t)tok * NHID;
      u16* dst = LeafVals + (size_t)r * NHID;
      float4 v = *reinterpret_cast<const float4*>(src + i);
      ushort4 o = {f2b(v.x), f2b(v.y), f2b(v.z), f2b(v.w)};
      *reinterpret_cast<ushort4*>(dst + i) = o;
    }
    return;
  }
  if (blockIdx.x != 0) {
    // W conversion
    int id = (blockIdx.x - 1) * 768 + threadIdx.x;
    int stride = NCONV * 768;
    for (int i = id; i < (NHID * K2) / 4; i += stride) {
      float4 v = reinterpret_cast<const float4*>(W)[i];
      ushort4 o = {f2b(v.x), f2b(v.y), f2b(v.z), f2b(v.w)};
      reinterpret_cast<ushort4*>(Wbf)[i] = o;
    }
    return;
  }

  // ---- block 0: parallel structural parse (batch 0; structure invariant) ----
  __shared__ int tok[SLEN];
  __shared__ int SC[SLEN];        // packed scan: depth<<20 | leaf<<10 | close
  __shared__ short A[16 * SLEN];  // per-depth max-scan; later lvl overlay
  __shared__ int cntLoc[MAXL];

  int t = threadIdx.x;
  tok[t] = tokens[t * B + 0];
  if (t < MAXL) cntLoc[t] = 0;
  __syncthreads();

  int tk = tok[t];
  bool isO = (tk == 0), isC = (tk == 1);
  bool isL = !isO && !isC && (tk != PADTOK);
  int delta = isO ? 1 : (isC ? -1 : 0);
  SC[t] = (delta << 20) + ((isL ? 1 : 0) << 10) + (isC ? 1 : 0);
  __syncthreads();

  for (int off = 1; off < SLEN; off <<= 1) {   // packed inclusive scan
    int v = SC[t];
    int u = (t >= off) ? SC[t - off] : 0;
    __syncthreads();
    SC[t] = v + u;
    __syncthreads();
  }

  int S = SC[t];
  int depth = S >> 20; if (depth > 15) depth = 15;
  int clIdx = S & 1023;

  // per-depth max scans: A[d][t] = max{t' <= t : D[t'] == d}, else -1
#pragma unroll
  for (int d = 0; d < 16; ++d) A[d * SLEN + t] = (depth == d) ? (short)t : (short)-1;
  __syncthreads();
  for (int off = 1; off < SLEN; off <<= 1) {
    short vv[16];
#pragma unroll
    for (int d = 0; d < 16; ++d) {
      short a = A[d * SLEN + t];
      if (t >= off) { short b2 = A[d * SLEN + t - off]; a = (a > b2) ? a : b2; }
      vv[d] = a;
    }
    __syncthreads();
#pragma unroll
    for (int d = 0; d < 16; ++d) A[d * SLEN + t] = vv[d];
    __syncthreads();
  }

  // per-CLOSE child refs (leaf children -> POSITION encoding)
  int myid = -1, lref = 0, rref = 0, lce = -1;
  bool rIsLeaf = false, lIsLeaf = false;
  if (isC && t >= 3) {
    myid = clIdx - 1;
    int tm1 = tok[t - 1];
    rIsLeaf = (tm1 != 1);
    rref = rIsLeaf ? (0x40000000 | (t - 1)) : ((SC[t - 1] & 1023) - 1);
    int dd = depth + 1; if (dd > 15) dd = 15;
    lce = rIsLeaf ? (t - 2) : (int)A[dd * SLEN + (t - 2)];
    if (lce >= 0) {
      lIsLeaf = (tok[lce] != 1);
      lref = lIsLeaf ? (0x40000000 | lce) : ((SC[lce] & 1023) - 1);
    }
  }
  __syncthreads();

  // level sweeps (lvl overlays A row 0)
  short* lvl = A;
  lvl[t] = isC ? (short)1 : (short)0;
  __syncthreads();
  int lv = 1;
  for (int it = 0; it < 15; ++it) {
    if (myid >= 0) {
      int ll = lIsLeaf ? 0 : (int)lvl[lce];
      int rr = rIsLeaf ? 0 : (int)lvl[t - 1];
      lv = (ll > rr ? ll : rr) + 1;
    }
    __syncthreads();
    if (myid >= 0) lvl[t] = (short)lv;
    __syncthreads();
  }
  if (lv > 15) lv = 15;

  if (myid >= 0 && myid < NINT) {
    int slot = atomicAdd(&cntLoc[lv], 1);
    if (slot < MAXN)
      nodes[lv * MAXN + slot] = make_int4(lref, rref, myid, 0);
  }
  __syncthreads();

  if (t == 0) {
    int ncount = SC[SLEN - 1] & 1023;
    rootArr[0] = (ncount > 0) ? (ncount - 1 < NINT ? ncount - 1 : NINT - 1)
                              : 0x40000000;  // degenerate: root = leaf at pos 0
  }
  if (t >= 1 && t < MAXL) cnt[t] = (cntLoc[t] < MAXN) ? cntLoc[t] : MAXN;
}

// ---------------------------------------------------------------------------
// Per-level combine: out = tanh(concat(valL,valR) @ W^T + b), bf16 MFMA.
// 128x128 tile, 4 waves. NEW (T3+T4): BK=32, 4 LDS buffers, 3-deep prefetch
// with COUNTED vmcnt waits — steady state keeps 12 wave-loads in flight and
// waits vmcnt(8) per step (drain only the oldest stage), so ~600-900 cy
// L3/HBM latency hides under 3 compute phases. T5: setprio around MFMAs.
// nt = tile&7 with grid%8==0 keeps each XCD on one 512 KB W-stripe (L2-hot).
// ---------------------------------------------------------------------------
__launch_bounds__(256, 2)
__global__ void combine_level(const u16* __restrict__ Wbf,
                              const float* __restrict__ bias,
                              const int* __restrict__ cnt,
                              const int4* __restrict__ nodes,
                              const int* __restrict__ rootArr,
                              const u16* __restrict__ LeafVals,
                              u16* __restrict__ Vals,     // [B][NINT][NHID] bf16
                              float* __restrict__ out,    // [B][NHID] fp32
                              const int* __restrict__ tokens,
                              const float* __restrict__ emb,
                              int level) {
  __shared__ short As[4][4096];   // 4 stages x (128 rows x 32 k)
  __shared__ short Bs[4][4096];
  __shared__ const u16* sL[128];
  __shared__ const u16* sR[128];
  __shared__ int sOut[128];
  __shared__ int sRoot[128];

  int rootId = rootArr[0];
  if (rootId & 0x40000000) {       // degenerate single-leaf tree
    if (level != 1) return;
    int pos = rootId & 0xFFFF;
    for (int b = blockIdx.x; b < B; b += gridDim.x) {
      int tokv = tokens[pos * B + b];
      for (int i = threadIdx.x; i < NHID; i += 256)
        out[(size_t)b * NHID + i] = emb[(size_t)tokv * NHID + i];
    }
    return;
  }

  int cnt0 = cnt[level];
  if (cnt0 <= 0) return;
  int rowsTotal = B * cnt0;
  int mTiles = (rowsTotal + 127) >> 7;
  int totalTiles = mTiles * 8;
  int tid = threadIdx.x;
  int lane = tid & 63, wave = tid >> 6;
  int wm = wave & 1, wn = wave >> 1;

  for (int tile = blockIdx.x; tile < totalTiles; tile += gridDim.x) {
    int mt = tile >> 3, nt = tile & 7;
    int m0 = mt << 7, n0 = nt << 7;
    __syncthreads();  // protect sL/sR/sOut vs previous tile's readers
    if (tid < 128) {
      int r = m0 + tid;
      const u16* lp = Wbf; const u16* rp = Wbf; int ov = -1, rf = -1;
      if (r < rowsTotal) {
        int bb = r / cnt0, j = r - bb * cnt0;
        int4 rec = nodes[level * MAXN + j];
        int lr = rec.x, rr = rec.y;
        lp = (lr & 0x40000000) ? LeafVals + (size_t)(bb * SLEN + (lr & 0xFFFF)) * NHID
                               : Vals + ((size_t)bb * NINT + lr) * NHID;
        rp = (rr & 0x40000000) ? LeafVals + (size_t)(bb * SLEN + (rr & 0xFFFF)) * NHID
                               : Vals + ((size_t)bb * NINT + rr) * NHID;
        ov = bb * NINT + rec.z;
        if (rec.z == rootId) rf = bb * NHID;
      }
      sL[tid] = lp; sR[tid] = rp; sOut[tid] = ov; sRoot[tid] = rf;
    }
    __syncthreads();

    int kq = (tid & 3) * 8;
    const u16* a0L = sL[tid >> 2] + kq;        const u16* a0R = sR[tid >> 2] + kq;
    const u16* a1L = sL[64 + (tid >> 2)] + kq; const u16* a1R = sR[64 + (tid >> 2)] + kq;
    const u16* b0 = Wbf + (size_t)(n0 + (tid >> 2)) * K2 + kq;
    const u16* b1 = Wbf + (size_t)(n0 + 64 + (tid >> 2)) * K2 + kq;

    f32x4 acc[4][4];
#pragma unroll
    for (int i = 0; i < 4; ++i)
#pragma unroll
      for (int j = 0; j < 4; ++j) acc[i][j] = {0.f, 0.f, 0.f, 0.f};

    int aBase = (wm * 64 + (lane & 15)) * 32 + (lane >> 4) * 8;
    int bBase = (wn * 64 + (lane & 15)) * 32 + (lane >> 4) * 8;

    // stage one BK=32 panel into buffer `buf`: 4 wave-VMEM ops
    auto STAGE = [&](int buf, int k0) {
      const u16* sa0 = (k0 < NHID) ? (a0L + k0) : (a0R + (k0 - NHID));
      const u16* sa1 = (k0 < NHID) ? (a1L + k0) : (a1R + (k0 - NHID));
      short* Ad = &As[buf][0] + wave * 512;   // wave-uniform dest
      short* Bd = &Bs[buf][0] + wave * 512;
      glds16(sa0, Ad);
      glds16(sa1, Ad + 2048);
      glds16(b0 + k0, Bd);
      glds16(b1 + k0, Bd + 2048);
    };
    // compute one BK=32 panel: 8 ds_read_b128 + 16 MFMA per thread
    auto COMPUTE = [&](int buf) {
      short8 af[4], bw[4];
#pragma unroll
      for (int mi = 0; mi < 4; ++mi)
        af[mi] = *reinterpret_cast<const short8*>(&As[buf][0] + aBase + mi * 512);
#pragma unroll
      for (int ni = 0; ni < 4; ++ni)
        bw[ni] = *reinterpret_cast<const short8*>(&Bs[buf][0] + bBase + ni * 512);
      __builtin_amdgcn_s_setprio(1);
#pragma unroll
      for (int mi = 0; mi < 4; ++mi)
#pragma unroll
        for (int ni = 0; ni < 4; ++ni)
          acc[mi][ni] = __builtin_amdgcn_mfma_f32_16x16x32_bf16(
              af[mi], bw[ni], acc[mi][ni], 0, 0, 0);
      __builtin_amdgcn_s_setprio(0);
    };

    // 3-deep software pipeline over 64 K-steps of 32.
    // Steady state: 12 wave-loads in flight; wait vmcnt(8) = oldest stage done.
    STAGE(0, 0); STAGE(1, 32); STAGE(2, 64);
    for (int t = 0; t < 61; ++t) {
      asm volatile("s_waitcnt vmcnt(8)" ::: "memory");
      __builtin_amdgcn_s_barrier();
      COMPUTE(t & 3);
      STAGE((t + 3) & 3, (t + 3) * 32);   // overwrites buf freed at this barrier
    }
    asm volatile("s_waitcnt vmcnt(8)" ::: "memory");
    __builtin_amdgcn_s_barrier();
    COMPUTE(61 & 3);
    asm volatile("s_waitcnt vmcnt(4)" ::: "memory");
    __builtin_amdgcn_s_barrier();
    COMPUTE(62 & 3);
    asm volatile("s_waitcnt vmcnt(0)" ::: "memory");
    __builtin_amdgcn_s_barrier();
    COMPUTE(63 & 3);

    // epilogue: C/D layout col=lane&15 (n), row=(lane>>4)*4+reg (m)
#pragma unroll
    for (int ni = 0; ni < 4; ++ni) {
      int n = n0 + wn * 64 + ni * 16 + (lane & 15);
      float bv = bias[n];
#pragma unroll
      for (int mi = 0; mi < 4; ++mi) {
#pragma unroll
        for (int reg = 0; reg < 4; ++reg) {
          int mloc = wm * 64 + mi * 16 + (lane >> 4) * 4 + reg;
          int ov = sOut[mloc];
          if (ov >= 0) {
            float v = fast_tanh(acc[mi][ni][reg] + bv);
            Vals[(size_t)ov * NHID + n] = f2b(v);
            int rf = sRoot[mloc];
            if (rf >= 0) out[rf + n] = v;  // root row -> final output (fp32)
          }
        }
      }
    }
  }
}

extern "C" void kernel_launch(void* const* d_in, const int* in_sizes, int n_in,
                              void* d_out, int out_size, void* d_ws, size_t ws_size,
                              hipStream_t stream) {
  const int* tokens = (const int*)d_in[0];
  const float* emb  = (const float*)d_in[1];
  const float* W    = (const float*)d_in[2];
  const float* bias = (const float*)d_in[3];
  float* out = (float*)d_out;

  char* ws = (char*)d_ws;
  // ws layout (bytes):
  //   cnt      @ 0           64 B
  //   rootArr  @ 4096        4 B
  //   nodes    @ 12288       64 KB  ([MAXL][MAXN] int4, batch-invariant)
  //   Wbf      @ 131072      4 MB
  //   LeafVals @ 4325376     96 MB  (position-keyed: [B][SLEN][NHID] bf16)
  //   Vals     @ +96MB       32 MB  -> total ~138.5 MB
  int* cnt      = (int*)ws;
  int* rootArr  = (int*)(ws + 4096);
  int4* nodes   = (int4*)(ws + 12288);
  u16* Wbf      = (u16*)(ws + 131072);
  u16* LeafVals = (u16*)(ws + 4325376);
  u16* Vals     = (u16*)(ws + 4325376 + (size_t)B * SLEN * NHID * 2);

  // Dispatch 1: parse (block 0) + W conversion (blocks 1..128) + leaf gather
  // (2048 grid-strided blocks) all overlapped.
  parse_leaf_wconv<<<1 + NCONV + LEAFB, 768, 0, stream>>>(
      tokens, emb, W, cnt, rootArr, nodes, Wbf, LeafVals);

  // Dispatches 2..10: one per level (stream-ordered dependencies).
  for (int L = 1; L <= 9; ++L) {  // balanced 256-leaf tree: levels 1..8; 9 = guard
    int expRows = B * (L <= 8 ? (256 >> L) : 1);
    int mT = (expRows + 127) / 128;
    combine_level<<<mT * 8, 256, 0, stream>>>(Wbf, bias, cnt, nodes, rootArr,
                                              LeafVals, Vals, out, tokens, emb, L);
  }
}